// Round 10
// baseline (193.427 us; speedup 1.0000x reference)
//
#include <hip/hip_runtime.h>
#include <math.h>

#define B_ 2
#define C_ 32
#define D_ 32
#define H_ 32
#define W_ 64
#define HW_ (H_*W_)         // 2048
#define DHW_ (D_*H_*W_)     // 65536
#define CDHW_ (C_*DHW_)     // 2097152
#define NSP_ DHW_           // spatial points per batch
#define BN_N_ (B_*DHW_)     // 131072
#define BORDER 1e-3
#define RS 516              // padded LDS ring stride (floats): wl*4 bank offset, 16B-aligned

// ws layout: Mw [b][p][c] @0 (16MB), Mh @16MB, Md @32MB, reduction @48MB:
// npart[1024] double2 @ +256, spart[512] double2 @ +256+16384. All written before read.
#define MH_OFF  (16u<<20)
#define MD_OFF  (32u<<20)
#define RED_OFF (48u<<20)

// ---------------- threshold stats (channel-split: 2 threads per point) ----------------
__global__ __launch_bounds__(256) void k_norm(const float* __restrict__ x, double2* __restrict__ npart) {
    int tid = blockIdx.x * 256 + threadIdx.x;       // 262144 threads
    int ln = threadIdx.x & 63;
    int half = ln >> 5, lp = ln & 31;
    int p = (tid >> 6) * 32 + lp;                   // 131072 points, 2x coverage
    int b = p >> 16, pp = p & 65535;
    int d = pp >> 11, h = (pp >> 6) & 31, w = pp & 63;
    int pf = ((d ^ 16) << 11) | ((h ^ 16) << 6) | (w ^ 32);
    const float* xb = x + (size_t)b * CDHW_ + (size_t)half * 16 * DHW_;
    double s = 0.0;
#pragma unroll
    for (int c = 0; c < 16; ++c) {
        float a  = xb[c * DHW_ + pp];
        float bb = xb[c * DHW_ + pf];
        s += fabs((double)a - (double)bb);
    }
    double st = s + __shfl_xor(s, 32, 64);          // full 32-ch sum (both halves hold it)
    double s2 = st * st;
    for (int off = 32; off; off >>= 1) {
        st += __shfl_down(st, off, 64);
        s2 += __shfl_down(s2, off, 64);
    }
    __shared__ double ls[4], ls2[4];
    int wv = threadIdx.x >> 6;
    if (ln == 0) { ls[wv] = st; ls2[wv] = s2; }
    __syncthreads();
    if (threadIdx.x == 0) {                          // each point counted twice -> *0.5 (exact)
        double2 o;
        o.x = ((ls[0] + ls[1]) + (ls[2] + ls[3])) * 0.5;
        o.y = ((ls2[0] + ls2[1]) + (ls2[2] + ls2[3])) * 0.5;
        npart[blockIdx.x] = o;
    }
}

// ---------------- per-block redundant thr reduce + f32 gate bounds ----------------
// fb[b*4 + {0,1,2}] = {tlo, thi, tmid}; f64 path taken inside [tlo,thi] (superset of |ds-thr|<BORDER);
// outside, f32 cmp vs tmid provably equals the f64 cmp (|ds-thr|>1e-3 >> ulp).
__device__ __forceinline__ void thr_reduce(const double2* __restrict__ npart, double* thrs, float* fb,
                                           double* ls, double* lq, int t) {
    {
        double s = 0.0, q = 0.0;
#pragma unroll
        for (int i = 0; i < 4; ++i) {
            double2 v = npart[t * 4 + i];
            s += v.x; q += v.y;
        }
        for (int off = 32; off; off >>= 1) {
            s += __shfl_down(s, off, 64);
            q += __shfl_down(q, off, 64);
        }
        if ((t & 63) == 0) { ls[t >> 6] = s; lq[t >> 6] = q; }
    }
    __syncthreads();
    if (t < 2) {
        double sum = ls[2 * t] + ls[2 * t + 1];
        double sq  = lq[2 * t] + lq[2 * t + 1];
        double n = (double)NSP_;
        double mean = sum / n;
        double var = (sq - sum * sum / n) / (n - 1.0);   // ddof=1
        if (var < 0.0) var = 0.0;
        double thrv = mean - sqrt(var);
        thrs[t] = thrv;
        fb[t * 4 + 0] = (float)(thrv - BORDER * 1.01);
        fb[t * 4 + 1] = (float)(thrv + BORDER * 1.01);
        fb[t * 4 + 2] = (float)thrv;
    }
    __syncthreads();
}

__device__ __forceinline__ float dist16(const float* col, const float* nb) {
    float d0 = 0.f, d1 = 0.f, d2 = 0.f, d3 = 0.f;
#pragma unroll
    for (int c = 0; c < 16; c += 4) {
        d0 += fabsf(col[c+0] - nb[c+0]);
        d1 += fabsf(col[c+1] - nb[c+1]);
        d2 += fabsf(col[c+2] - nb[c+2]);
        d3 += fabsf(col[c+3] - nb[c+3]);
    }
    return (d0 + d1) + (d2 + d3);
}

// H/D ring body. 256 threads, 8 rings (one parity). Lane map: wave holds ALL 16 positions
// of 4 (wl,half) combos -> pair-symmetric decisions via one mask shuffle.
template<int AS, int FS>
__device__ __forceinline__ void hd_ring(const float* __restrict__ x, float* __restrict__ M,
                                        const double* thrs, const float* fb, float* L, int local, int t) {
    int par = local & 1, wt = (local >> 1) & 7, F = (local >> 4) & 31, b = local >> 9;
    int w0 = wt * 8;
    double thr = thrs[b];
    float tlo = fb[b*4], thi = fb[b*4+1], tmf = fb[b*4+2];
    const float* xb = x + (size_t)b * CDHW_ + (size_t)F * FS + w0;
#pragma unroll
    for (int it = 0; it < 4; ++it) {
        int f = it * 256 + t;                        // 0..1023 float4s
        int c = f >> 5, rem = f & 31, j = rem >> 1, wq = rem & 1;
        float4 v = *(const float4*)(xb + (size_t)c * DHW_ + (size_t)(2 * j + par) * AS + wq * 4);
        int sl = (((c >> 2) ^ (j & 7)) << 2) + (c & 3);
        int rb = (wq * 4) * RS + j * 32 + sl;
        L[rb] = v.x; L[rb + RS] = v.y; L[rb + 2*RS] = v.z; L[rb + 3*RS] = v.w;
    }
    __syncthreads();
    int ln = t & 63, wave = t >> 6;
    int pos = ln >> 2, c2 = ln & 3;
    int wl = wave * 2 + (c2 >> 1), half = c2 & 1;
    const float* Lr = L + wl * RS;
    int qb = half * 4;
    float col[16], Mv[16], nb[16];
#pragma unroll
    for (int k = 0; k < 4; ++k) {
        float4 cv = *(const float4*)(Lr + pos * 32 + (((qb + k) ^ (pos & 7)) << 2));
        col[4*k] = cv.x; col[4*k+1] = cv.y; col[4*k+2] = cv.z; col[4*k+3] = cv.w;
    }
#pragma unroll
    for (int c = 0; c < 16; ++c) Mv[c] = col[c];
    unsigned mymask = 0;
    // forward shifts s=1..8 (s=8 self-paired): compute dist + gate, record decision bit
#pragma unroll
    for (int s = 1; s <= 8; ++s) {
        int jj = (pos - s) & 15;
#pragma unroll
        for (int k = 0; k < 4; ++k) {
            float4 nv = *(const float4*)(Lr + jj * 32 + (((qb + k) ^ (jj & 7)) << 2));
            nb[4*k] = nv.x; nb[4*k+1] = nv.y; nb[4*k+2] = nv.z; nb[4*k+3] = nv.w;
        }
        float dh = dist16(col, nb);
        float ds = dh + __shfl_xor(dh, 1, 64);       // half partner = lane^1
        bool border = (ds >= tlo) & (ds <= thi);
        bool cmp;
        if (__ballot(border)) {                      // rare exact path
            double d64h = 0.0;
#pragma unroll
            for (int c = 0; c < 16; ++c) d64h += fabs((double)col[c] - (double)nb[c]);
            double other = __shfl_xor(d64h, 1, 64);
            cmp = (d64h + other) < thr;
        } else {
            cmp = ds < tmf;
        }
        mymask |= (unsigned)cmp << s;
#pragma unroll
        for (int c = 0; c < 16; ++c) Mv[c] = (cmp && nb[c] > Mv[c]) ? nb[c] : Mv[c];
    }
    // reverse shifts s=9..15: decision = partner's bit (16-s); only load + merge
#pragma unroll
    for (int s = 9; s <= 15; ++s) {
        int jj = (pos - s) & 15;
        int pl = jj * 4 + c2;                        // partner lane (same wl/half, pos-s)
        int cr = (__shfl((int)mymask, pl, 64) >> (16 - s)) & 1;
#pragma unroll
        for (int k = 0; k < 4; ++k) {
            float4 nv = *(const float4*)(Lr + jj * 32 + (((qb + k) ^ (jj & 7)) << 2));
            nb[4*k] = nv.x; nb[4*k+1] = nv.y; nb[4*k+2] = nv.z; nb[4*k+3] = nv.w;
        }
        bool cmpr = (cr != 0);
#pragma unroll
        for (int c = 0; c < 16; ++c) Mv[c] = (cmpr && nb[c] > Mv[c]) ? nb[c] : Mv[c];
    }
    size_t p = (size_t)F * FS + (size_t)(2 * pos + par) * AS + w0 + wl;
    float* mp = M + ((size_t)b * 65536 + p) * 32 + half * 16;
#pragma unroll
    for (int k = 0; k < 4; ++k) {
        float4 o; o.x = Mv[4*k]; o.y = Mv[4*k+1]; o.z = Mv[4*k+2]; o.w = Mv[4*k+3];
        *(float4*)(mp + 4 * k) = o;
    }
}

// ---------------- unified passes kernel: blk<1024 -> W, <2048 -> H, else D ----------------
__global__ __launch_bounds__(256) void k_passes(const float* __restrict__ x, const double2* __restrict__ npart,
                                                float* __restrict__ Mw, float* __restrict__ Mh,
                                                float* __restrict__ Md) {
    __shared__ __align__(16) float L[4128];          // max(8*RS, 4096)
    __shared__ double ls[4], lq[4], thrs[2];
    __shared__ float fb[8];
    int t = threadIdx.x;
    thr_reduce(npart, thrs, fb, ls, lq, t);
    int blk = blockIdx.x;
    if (blk < 1024) {
        // ---- W-axis: 4 rings (2 lines x 2 parities); one wave per ring (32 pos x 2 half) ----
#pragma unroll
        for (int it = 0; it < 4; ++it) {
            int f = it * 256 + t;                    // 0..1023 float4s
            int ll = f >> 9;
            int l = blk * 2 + ll;
            int c = (f >> 4) & 31, wq = f & 15;
            const float* lb = x + (size_t)(l >> 10) * CDHW_ + ((l >> 5) & 31) * HW_ + (l & 31) * W_;
            float4 v = *(const float4*)(lb + (size_t)c * DHW_ + wq * 4);
            int cq = c >> 2, cr = c & 3;
            const float* ve = (const float*)&v;
#pragma unroll
            for (int e = 0; e < 4; ++e) {
                int wv2 = wq * 4 + e;
                int p = wv2 >> 1, par = wv2 & 1;
                L[(ll * 2 + par) * 1024 + p * 32 + (((cq ^ (p & 7)) << 2) | cr)] = ve[e];
            }
        }
        __syncthreads();
        int ring = t >> 6, ln = t & 63;
        int pos = ln >> 1, half = ln & 1;
        int ll = ring >> 1, par = ring & 1;
        int l = blk * 2 + ll;
        int b = l >> 10, d = (l >> 5) & 31, h = l & 31;
        double thr = thrs[b];
        float tlo = fb[b*4], thi = fb[b*4+1], tmf = fb[b*4+2];
        const float* Lr = L + ring * 1024;
        int qb = half * 4;
        float col[16], Mv[16], nb[16];
#pragma unroll
        for (int k = 0; k < 4; ++k) {
            float4 cv = *(const float4*)(Lr + pos * 32 + (((qb + k) ^ (pos & 7)) << 2));
            col[4*k] = cv.x; col[4*k+1] = cv.y; col[4*k+2] = cv.z; col[4*k+3] = cv.w;
        }
#pragma unroll
        for (int c = 0; c < 16; ++c) Mv[c] = col[c];
        for (int s = 1; s <= 15; ++s) {              // pairs (s, 32-s)
            int jf = (pos - s) & 31;
#pragma unroll
            for (int k = 0; k < 4; ++k) {
                float4 nv = *(const float4*)(Lr + jf * 32 + (((qb + k) ^ (jf & 7)) << 2));
                nb[4*k] = nv.x; nb[4*k+1] = nv.y; nb[4*k+2] = nv.z; nb[4*k+3] = nv.w;
            }
            float dh = dist16(col, nb);
            float ds = dh + __shfl_xor(dh, 1, 64);   // half partner = ln^1
            bool border = (ds >= tlo) & (ds <= thi);
            bool cmp;
            if (__ballot(border)) {
                double d64h = 0.0;
#pragma unroll
                for (int c = 0; c < 16; ++c) d64h += fabs((double)col[c] - (double)nb[c]);
                double other = __shfl_xor(d64h, 1, 64);
                cmp = (d64h + other) < thr;
            } else {
                cmp = ds < tmf;
            }
#pragma unroll
            for (int c = 0; c < 16; ++c) Mv[c] = (cmp && nb[c] > Mv[c]) ? nb[c] : Mv[c];
            int cr2 = __shfl(cmp ? 1 : 0, ((pos + s) & 31) * 2 + half, 64);   // partner's decision
            int jr = (pos + s) & 31;
#pragma unroll
            for (int k = 0; k < 4; ++k) {
                float4 nv = *(const float4*)(Lr + jr * 32 + (((qb + k) ^ (jr & 7)) << 2));
                nb[4*k] = nv.x; nb[4*k+1] = nv.y; nb[4*k+2] = nv.z; nb[4*k+3] = nv.w;
            }
            bool cmpr = (cr2 != 0);
#pragma unroll
            for (int c = 0; c < 16; ++c) Mv[c] = (cmpr && nb[c] > Mv[c]) ? nb[c] : Mv[c];
        }
        {   // s = 16 self-paired
            int jj = (pos + 16) & 31;
#pragma unroll
            for (int k = 0; k < 4; ++k) {
                float4 nv = *(const float4*)(Lr + jj * 32 + (((qb + k) ^ (jj & 7)) << 2));
                nb[4*k] = nv.x; nb[4*k+1] = nv.y; nb[4*k+2] = nv.z; nb[4*k+3] = nv.w;
            }
            float dh = dist16(col, nb);
            float ds = dh + __shfl_xor(dh, 1, 64);
            bool border = (ds >= tlo) & (ds <= thi);
            bool cmp;
            if (__ballot(border)) {
                double d64h = 0.0;
#pragma unroll
                for (int c = 0; c < 16; ++c) d64h += fabs((double)col[c] - (double)nb[c]);
                double other = __shfl_xor(d64h, 1, 64);
                cmp = (d64h + other) < thr;
            } else {
                cmp = ds < tmf;
            }
#pragma unroll
            for (int c = 0; c < 16; ++c) Mv[c] = (cmp && nb[c] > Mv[c]) ? nb[c] : Mv[c];
        }
        size_t ppt = (size_t)d * HW_ + h * W_ + 2 * pos + par;
        float* mp = Mw + ((size_t)b * 65536 + ppt) * 32 + half * 16;
#pragma unroll
        for (int k = 0; k < 4; ++k) {
            float4 o; o.x = Mv[4*k]; o.y = Mv[4*k+1]; o.z = Mv[4*k+2]; o.w = Mv[4*k+3];
            *(float4*)(mp + 4 * k) = o;
        }
    } else if (blk < 2048) {
        hd_ring<W_, HW_>(x, Mh, thrs, fb, L, blk - 1024, t);   // H pass (F = d)
    } else {
        hd_ring<HW_, W_>(x, Md, thrs, fb, L, blk - 2048, t);   // D pass (F = h)
    }
}

// ---------------- 1x1x1 conv (64 -> 32); z2 = relu(max3(Mw,Mh,Md) - x) inline ----------------
__global__ __launch_bounds__(256, 4) void k_conv(const float* __restrict__ x,
                                                 const float* __restrict__ Mw, const float* __restrict__ Mh,
                                                 const float* __restrict__ Md,
                                                 const float* __restrict__ w, const float* __restrict__ bias,
                                                 float* __restrict__ y) {
    int t = threadIdx.x;
    int blk = blockIdx.x;                            // 0..2047
    int b = blk >> 10;
    int p0 = (blk & 1023) * 64;
    int og = __builtin_amdgcn_readfirstlane(t >> 6); // wave-uniform -> weights stay scalar
    int pl = t & 63;
    const float* xb = x + (size_t)b * CDHW_ + p0 + pl;
    size_t moff = ((size_t)b * 65536 + p0 + pl) * 32;
    const float4* mw = (const float4*)(Mw + moff);
    const float4* mh = (const float4*)(Mh + moff);
    const float4* md = (const float4*)(Md + moff);
    const float* wo = w + og * 512;                  // SGPR base -> s_load weights
    const float* bo = bias + og * 8;
    float a[8], xv[32];
#pragma unroll
    for (int k = 0; k < 8; ++k) a[k] = bo[k];
#pragma unroll
    for (int c = 0; c < 32; c += 4) {                // x half (L1-reused across the 4 waves)
        xv[c+0] = xb[(size_t)(c+0) * DHW_];
        xv[c+1] = xb[(size_t)(c+1) * DHW_];
        xv[c+2] = xb[(size_t)(c+2) * DHW_];
        xv[c+3] = xb[(size_t)(c+3) * DHW_];
#pragma unroll
        for (int k = 0; k < 8; ++k) {
            a[k] = fmaf(wo[k*64 + c+0], xv[c+0], a[k]);
            a[k] = fmaf(wo[k*64 + c+1], xv[c+1], a[k]);
            a[k] = fmaf(wo[k*64 + c+2], xv[c+2], a[k]);
            a[k] = fmaf(wo[k*64 + c+3], xv[c+3], a[k]);
        }
    }
#pragma unroll
    for (int q = 0; q < 8; ++q) {                    // z2 half (3x contiguous 128B/point + max3)
        float4 vw = mw[q], vh = mh[q], vd = md[q];
        float z0 = fmaxf(fmaxf(fmaxf(vw.x, vh.x), vd.x) - xv[4*q+0], 0.f);
        float z1 = fmaxf(fmaxf(fmaxf(vw.y, vh.y), vd.y) - xv[4*q+1], 0.f);
        float z2 = fmaxf(fmaxf(fmaxf(vw.z, vh.z), vd.z) - xv[4*q+2], 0.f);
        float z3 = fmaxf(fmaxf(fmaxf(vw.w, vh.w), vd.w) - xv[4*q+3], 0.f);
#pragma unroll
        for (int k = 0; k < 8; ++k) {
            a[k] = fmaf(wo[k*64 + 32 + q*4 + 0], z0, a[k]);
            a[k] = fmaf(wo[k*64 + 32 + q*4 + 1], z1, a[k]);
            a[k] = fmaf(wo[k*64 + 32 + q*4 + 2], z2, a[k]);
            a[k] = fmaf(wo[k*64 + 32 + q*4 + 3], z3, a[k]);
        }
    }
    float* yb = y + (size_t)b * CDHW_ + p0 + pl;
#pragma unroll
    for (int k = 0; k < 8; ++k) yb[(size_t)(og * 8 + k) * DHW_] = a[k];
}

// ---------------- BN batch stats from y -> per-block partials ----------------
__global__ __launch_bounds__(256) void k_stats(const float* __restrict__ y, double2* __restrict__ spart) {
    int o = blockIdx.y, ch = blockIdx.x;
    float s = 0.f, q = 0.f;
#pragma unroll
    for (int b = 0; b < 2; ++b) {
        const float4* yp = (const float4*)(y + (size_t)b * CDHW_ + (size_t)o * DHW_ + ch * 4096);
#pragma unroll
        for (int i = 0; i < 4; ++i) {
            float4 v = yp[i * 256 + threadIdx.x];
            s += ((v.x + v.y) + (v.z + v.w));
            q += ((v.x*v.x + v.y*v.y) + (v.z*v.z + v.w*v.w));
        }
    }
    double sd = s, qd = q;
    for (int off = 32; off; off >>= 1) {
        sd += __shfl_down(sd, off, 64);
        qd += __shfl_down(qd, off, 64);
    }
    __shared__ double ls[4], lq[4];
    int wv = threadIdx.x >> 6;
    if ((threadIdx.x & 63) == 0) { ls[wv] = sd; lq[wv] = qd; }
    __syncthreads();
    if (threadIdx.x == 0) {
        double2 out;
        out.x = (ls[0] + ls[1]) + (ls[2] + ls[3]);
        out.y = (lq[0] + lq[1]) + (lq[2] + lq[3]);
        spart[o * 16 + ch] = out;
    }
}

// ---------------- BN normalize + exact GELU, in-place ----------------
__global__ __launch_bounds__(256) void k_out(float* __restrict__ y, const double2* __restrict__ spart,
                                             const float* __restrict__ gamma, const float* __restrict__ beta) {
    int idx = blockIdx.x * 256 + threadIdx.x;       // over 1,048,576 float4
    int o = (blockIdx.x >> 6) & 31;                  // wave-uniform channel
    double sm = 0.0, sq = 0.0;
#pragma unroll
    for (int ch = 0; ch < 16; ++ch) {
        double2 v = spart[o * 16 + ch];
        sm += v.x; sq += v.y;
    }
    double mu = sm / (double)BN_N_;
    double var = sq / (double)BN_N_ - mu * mu;
    float rstd = (float)(1.0 / sqrt(var + 1e-5));
    float mu_f = (float)mu;
    float g = gamma[o], be = beta[o];
    float4 v = ((const float4*)y)[idx];
    float* vv = (float*)&v;
#pragma unroll
    for (int j = 0; j < 4; ++j) {
        float t = (vv[j] - mu_f) * rstd * g + be;
        vv[j] = 0.5f * t * (1.f + erff(t * 0.70710678118654752f));
    }
    ((float4*)y)[idx] = v;
}

extern "C" void kernel_launch(void* const* d_in, const int* in_sizes, int n_in,
                              void* d_out, int out_size, void* d_ws, size_t ws_size,
                              hipStream_t stream) {
    const float* x     = (const float*)d_in[0];
    const float* w     = (const float*)d_in[1];
    const float* bias  = (const float*)d_in[2];
    const float* gamma = (const float*)d_in[3];
    const float* beta  = (const float*)d_in[4];
    float* out = (float*)d_out;
    float* Mw = (float*)d_ws;
    float* Mh = (float*)((char*)d_ws + MH_OFF);
    float* Md = (float*)((char*)d_ws + MD_OFF);
    double2* npart = (double2*)((char*)d_ws + RED_OFF + 256);
    double2* spart = (double2*)((char*)d_ws + RED_OFF + 256 + 16384);

    k_norm  <<<1024, 256, 0, stream>>>(x, npart);
    k_passes<<<3072, 256, 0, stream>>>(x, npart, Mw, Mh, Md);
    k_conv  <<<2048, 256, 0, stream>>>(x, Mw, Mh, Md, w, bias, out);
    k_stats <<<dim3(16, 32), 256, 0, stream>>>(out, spart);
    k_out   <<<4096, 256, 0, stream>>>(out, spart, gamma, beta);
}

// Round 11
// 117.188 us; speedup vs baseline: 1.6506x; 1.6506x over previous
//
#include <hip/hip_runtime.h>
#include <math.h>

#define B_ 2
#define C_ 32
#define D_ 32
#define H_ 32
#define W_ 64
#define HW_ (H_*W_)         // 2048
#define DHW_ (D_*H_*W_)     // 65536
#define CDHW_ (C_*DHW_)     // 2097152
#define NSP_ DHW_           // spatial points per batch
#define BN_N_ (B_*DHW_)     // 131072
#define BORDER 1e-3
#define RS 516              // padded LDS ring stride (floats): wl*4 bank offset, 16B-aligned

// ws layout: Mw [b][p][c] @0 (16MB), Mh @16MB, Md @32MB, reduction @48MB:
// npart[1024] double2 @ +256, spart[512] double2 @ +256+16384. All written before read.
#define MH_OFF  (16u<<20)
#define MD_OFF  (32u<<20)
#define RED_OFF (48u<<20)

// ---------------- threshold stats (channel-split: 2 threads per point) ----------------
__global__ __launch_bounds__(256) void k_norm(const float* __restrict__ x, double2* __restrict__ npart) {
    int tid = blockIdx.x * 256 + threadIdx.x;       // 262144 threads
    int ln = threadIdx.x & 63;
    int half = ln >> 5, lp = ln & 31;
    int p = (tid >> 6) * 32 + lp;                   // 131072 points, 2x coverage
    int b = p >> 16, pp = p & 65535;
    int d = pp >> 11, h = (pp >> 6) & 31, w = pp & 63;
    int pf = ((d ^ 16) << 11) | ((h ^ 16) << 6) | (w ^ 32);
    const float* xb = x + (size_t)b * CDHW_ + (size_t)half * 16 * DHW_;
    double s = 0.0;
#pragma unroll
    for (int c = 0; c < 16; ++c) {
        float a  = xb[c * DHW_ + pp];
        float bb = xb[c * DHW_ + pf];
        s += fabs((double)a - (double)bb);
    }
    double st = s + __shfl_xor(s, 32, 64);          // full 32-ch sum (both halves hold it)
    double s2 = st * st;
    for (int off = 32; off; off >>= 1) {
        st += __shfl_down(st, off, 64);
        s2 += __shfl_down(s2, off, 64);
    }
    __shared__ double ls[4], ls2[4];
    int wv = threadIdx.x >> 6;
    if (ln == 0) { ls[wv] = st; ls2[wv] = s2; }
    __syncthreads();
    if (threadIdx.x == 0) {                          // each point counted twice -> *0.5 (exact)
        double2 o;
        o.x = ((ls[0] + ls[1]) + (ls[2] + ls[3])) * 0.5;
        o.y = ((ls2[0] + ls2[1]) + (ls2[2] + ls2[3])) * 0.5;
        npart[blockIdx.x] = o;
    }
}

// ---------------- per-block redundant thr reduce + f32 gate bounds ----------------
// fb[b*4 + {0,1,2}] = {tlo, thi, tmid}; f64 path taken inside [tlo,thi] (superset of |ds-thr|<BORDER);
// outside, f32 cmp vs tmid provably equals the f64 cmp (|ds-thr|>1e-3 >> f32 dist error).
__device__ __forceinline__ void thr_reduce(const double2* __restrict__ npart, double* thrs, float* fb,
                                           double* ls, double* lq, int t) {
    {
        double s = 0.0, q = 0.0;
#pragma unroll
        for (int i = 0; i < 4; ++i) {
            double2 v = npart[t * 4 + i];
            s += v.x; q += v.y;
        }
        for (int off = 32; off; off >>= 1) {
            s += __shfl_down(s, off, 64);
            q += __shfl_down(q, off, 64);
        }
        if ((t & 63) == 0) { ls[t >> 6] = s; lq[t >> 6] = q; }
    }
    __syncthreads();
    if (t < 2) {
        double sum = ls[2 * t] + ls[2 * t + 1];
        double sq  = lq[2 * t] + lq[2 * t + 1];
        double n = (double)NSP_;
        double mean = sum / n;
        double var = (sq - sum * sum / n) / (n - 1.0);   // ddof=1
        if (var < 0.0) var = 0.0;
        double thrv = mean - sqrt(var);
        thrs[t] = thrv;
        fb[t * 4 + 0] = (float)(thrv - BORDER * 1.01);
        fb[t * 4 + 1] = (float)(thrv + BORDER * 1.01);
        fb[t * 4 + 2] = (float)thrv;
    }
    __syncthreads();
}

__device__ __forceinline__ float dist16(const float* col, const float* nb) {
    float d0 = 0.f, d1 = 0.f, d2 = 0.f, d3 = 0.f;
#pragma unroll
    for (int c = 0; c < 16; c += 4) {
        d0 += fabsf(col[c+0] - nb[c+0]);
        d1 += fabsf(col[c+1] - nb[c+1]);
        d2 += fabsf(col[c+2] - nb[c+2]);
        d3 += fabsf(col[c+3] - nb[c+3]);
    }
    return (d0 + d1) + (d2 + d3);
}

// H/D ring body. 256 threads, 8 rings (one parity). Lane map: wave holds ALL 16 positions
// of 4 (wl,half) combos -> pair-symmetric decisions via one mask shuffle.
// s-loops kept rolled (#pragma unroll 1) — full unroll blew VGPR 56->132 in round 10.
template<int AS, int FS>
__device__ __forceinline__ void hd_ring(const float* __restrict__ x, float* __restrict__ M,
                                        const double* thrs, const float* fb, float* L, int local, int t) {
    int par = local & 1, wt = (local >> 1) & 7, F = (local >> 4) & 31, b = local >> 9;
    int w0 = wt * 8;
    double thr = thrs[b];
    float tlo = fb[b*4], thi = fb[b*4+1], tmf = fb[b*4+2];
    const float* xb = x + (size_t)b * CDHW_ + (size_t)F * FS + w0;
#pragma unroll
    for (int it = 0; it < 4; ++it) {
        int f = it * 256 + t;                        // 0..1023 float4s
        int c = f >> 5, rem = f & 31, j = rem >> 1, wq = rem & 1;
        float4 v = *(const float4*)(xb + (size_t)c * DHW_ + (size_t)(2 * j + par) * AS + wq * 4);
        int sl = (((c >> 2) ^ (j & 7)) << 2) + (c & 3);
        int rb = (wq * 4) * RS + j * 32 + sl;
        L[rb] = v.x; L[rb + RS] = v.y; L[rb + 2*RS] = v.z; L[rb + 3*RS] = v.w;
    }
    __syncthreads();
    int ln = t & 63, wave = t >> 6;
    int pos = ln >> 2, c2 = ln & 3;
    int wl = wave * 2 + (c2 >> 1), half = c2 & 1;
    const float* Lr = L + wl * RS;
    int qb = half * 4;
    float col[16], Mv[16], nb[16];
#pragma unroll
    for (int k = 0; k < 4; ++k) {
        float4 cv = *(const float4*)(Lr + pos * 32 + (((qb + k) ^ (pos & 7)) << 2));
        col[4*k] = cv.x; col[4*k+1] = cv.y; col[4*k+2] = cv.z; col[4*k+3] = cv.w;
    }
#pragma unroll
    for (int c = 0; c < 16; ++c) Mv[c] = col[c];
    unsigned mymask = 0;
    // forward shifts s=1..8 (s=8 self-paired): compute dist + gate, record decision bit
#pragma unroll 1
    for (int s = 1; s <= 8; ++s) {
        int jj = (pos - s) & 15;
#pragma unroll
        for (int k = 0; k < 4; ++k) {
            float4 nv = *(const float4*)(Lr + jj * 32 + (((qb + k) ^ (jj & 7)) << 2));
            nb[4*k] = nv.x; nb[4*k+1] = nv.y; nb[4*k+2] = nv.z; nb[4*k+3] = nv.w;
        }
        float dh = dist16(col, nb);
        float ds = dh + __shfl_xor(dh, 1, 64);       // half partner = lane^1
        bool border = (ds >= tlo) & (ds <= thi);
        bool cmp;
        if (__ballot(border)) {                      // rare exact path
            double d64h = 0.0;
#pragma unroll
            for (int c = 0; c < 16; ++c) d64h += fabs((double)col[c] - (double)nb[c]);
            double other = __shfl_xor(d64h, 1, 64);
            cmp = (d64h + other) < thr;
        } else {
            cmp = ds < tmf;
        }
        mymask |= (unsigned)cmp << s;
#pragma unroll
        for (int c = 0; c < 16; ++c) Mv[c] = (cmp && nb[c] > Mv[c]) ? nb[c] : Mv[c];
    }
    // reverse shifts s=9..15: decision = partner's bit (16-s); only load + merge
#pragma unroll 1
    for (int s = 9; s <= 15; ++s) {
        int jj = (pos - s) & 15;
        int pl = jj * 4 + c2;                        // partner lane (same wl/half, pos-s)
        int cr = (__shfl((int)mymask, pl, 64) >> (16 - s)) & 1;
#pragma unroll
        for (int k = 0; k < 4; ++k) {
            float4 nv = *(const float4*)(Lr + jj * 32 + (((qb + k) ^ (jj & 7)) << 2));
            nb[4*k] = nv.x; nb[4*k+1] = nv.y; nb[4*k+2] = nv.z; nb[4*k+3] = nv.w;
        }
        bool cmpr = (cr != 0);
#pragma unroll
        for (int c = 0; c < 16; ++c) Mv[c] = (cmpr && nb[c] > Mv[c]) ? nb[c] : Mv[c];
    }
    size_t p = (size_t)F * FS + (size_t)(2 * pos + par) * AS + w0 + wl;
    float* mp = M + ((size_t)b * 65536 + p) * 32 + half * 16;
#pragma unroll
    for (int k = 0; k < 4; ++k) {
        float4 o; o.x = Mv[4*k]; o.y = Mv[4*k+1]; o.z = Mv[4*k+2]; o.w = Mv[4*k+3];
        *(float4*)(mp + 4 * k) = o;
    }
}

// ---------------- unified passes kernel: blk<1024 -> W, <2048 -> H, else D ----------------
__global__ __launch_bounds__(256) void k_passes(const float* __restrict__ x, const double2* __restrict__ npart,
                                                float* __restrict__ Mw, float* __restrict__ Mh,
                                                float* __restrict__ Md) {
    __shared__ __align__(16) float L[4128];          // max(8*RS, 4096)
    __shared__ double ls[4], lq[4], thrs[2];
    __shared__ float fb[8];
    int t = threadIdx.x;
    thr_reduce(npart, thrs, fb, ls, lq, t);
    int blk = blockIdx.x;
    if (blk < 1024) {
        // ---- W-axis: 4 rings (2 lines x 2 parities); one wave per ring (32 pos x 2 half) ----
#pragma unroll
        for (int it = 0; it < 4; ++it) {
            int f = it * 256 + t;                    // 0..1023 float4s
            int ll = f >> 9;
            int l = blk * 2 + ll;
            int c = (f >> 4) & 31, wq = f & 15;
            const float* lb = x + (size_t)(l >> 10) * CDHW_ + ((l >> 5) & 31) * HW_ + (l & 31) * W_;
            float4 v = *(const float4*)(lb + (size_t)c * DHW_ + wq * 4);
            int cq = c >> 2, cr = c & 3;
            const float* ve = (const float*)&v;
#pragma unroll
            for (int e = 0; e < 4; ++e) {
                int wv2 = wq * 4 + e;
                int p = wv2 >> 1, par = wv2 & 1;
                L[(ll * 2 + par) * 1024 + p * 32 + (((cq ^ (p & 7)) << 2) | cr)] = ve[e];
            }
        }
        __syncthreads();
        int ring = t >> 6, ln = t & 63;
        int pos = ln >> 1, half = ln & 1;
        int ll = ring >> 1, par = ring & 1;
        int l = blk * 2 + ll;
        int b = l >> 10, d = (l >> 5) & 31, h = l & 31;
        double thr = thrs[b];
        float tlo = fb[b*4], thi = fb[b*4+1], tmf = fb[b*4+2];
        const float* Lr = L + ring * 1024;
        int qb = half * 4;
        float col[16], Mv[16], nb[16];
#pragma unroll
        for (int k = 0; k < 4; ++k) {
            float4 cv = *(const float4*)(Lr + pos * 32 + (((qb + k) ^ (pos & 7)) << 2));
            col[4*k] = cv.x; col[4*k+1] = cv.y; col[4*k+2] = cv.z; col[4*k+3] = cv.w;
        }
#pragma unroll
        for (int c = 0; c < 16; ++c) Mv[c] = col[c];
#pragma unroll 1
        for (int s = 1; s <= 15; ++s) {              // pairs (s, 32-s)
            int jf = (pos - s) & 31;
#pragma unroll
            for (int k = 0; k < 4; ++k) {
                float4 nv = *(const float4*)(Lr + jf * 32 + (((qb + k) ^ (jf & 7)) << 2));
                nb[4*k] = nv.x; nb[4*k+1] = nv.y; nb[4*k+2] = nv.z; nb[4*k+3] = nv.w;
            }
            float dh = dist16(col, nb);
            float ds = dh + __shfl_xor(dh, 1, 64);   // half partner = ln^1
            bool border = (ds >= tlo) & (ds <= thi);
            bool cmp;
            if (__ballot(border)) {
                double d64h = 0.0;
#pragma unroll
                for (int c = 0; c < 16; ++c) d64h += fabs((double)col[c] - (double)nb[c]);
                double other = __shfl_xor(d64h, 1, 64);
                cmp = (d64h + other) < thr;
            } else {
                cmp = ds < tmf;
            }
#pragma unroll
            for (int c = 0; c < 16; ++c) Mv[c] = (cmp && nb[c] > Mv[c]) ? nb[c] : Mv[c];
            int cr2 = __shfl(cmp ? 1 : 0, ((pos + s) & 31) * 2 + half, 64);   // partner's decision
            int jr = (pos + s) & 31;
#pragma unroll
            for (int k = 0; k < 4; ++k) {
                float4 nv = *(const float4*)(Lr + jr * 32 + (((qb + k) ^ (jr & 7)) << 2));
                nb[4*k] = nv.x; nb[4*k+1] = nv.y; nb[4*k+2] = nv.z; nb[4*k+3] = nv.w;
            }
            bool cmpr = (cr2 != 0);
#pragma unroll
            for (int c = 0; c < 16; ++c) Mv[c] = (cmpr && nb[c] > Mv[c]) ? nb[c] : Mv[c];
        }
        {   // s = 16 self-paired
            int jj = (pos + 16) & 31;
#pragma unroll
            for (int k = 0; k < 4; ++k) {
                float4 nv = *(const float4*)(Lr + jj * 32 + (((qb + k) ^ (jj & 7)) << 2));
                nb[4*k] = nv.x; nb[4*k+1] = nv.y; nb[4*k+2] = nv.z; nb[4*k+3] = nv.w;
            }
            float dh = dist16(col, nb);
            float ds = dh + __shfl_xor(dh, 1, 64);
            bool border = (ds >= tlo) & (ds <= thi);
            bool cmp;
            if (__ballot(border)) {
                double d64h = 0.0;
#pragma unroll
                for (int c = 0; c < 16; ++c) d64h += fabs((double)col[c] - (double)nb[c]);
                double other = __shfl_xor(d64h, 1, 64);
                cmp = (d64h + other) < thr;
            } else {
                cmp = ds < tmf;
            }
#pragma unroll
            for (int c = 0; c < 16; ++c) Mv[c] = (cmp && nb[c] > Mv[c]) ? nb[c] : Mv[c];
        }
        size_t ppt = (size_t)d * HW_ + h * W_ + 2 * pos + par;
        float* mp = Mw + ((size_t)b * 65536 + ppt) * 32 + half * 16;
#pragma unroll
        for (int k = 0; k < 4; ++k) {
            float4 o; o.x = Mv[4*k]; o.y = Mv[4*k+1]; o.z = Mv[4*k+2]; o.w = Mv[4*k+3];
            *(float4*)(mp + 4 * k) = o;
        }
    } else if (blk < 2048) {
        hd_ring<W_, HW_>(x, Mh, thrs, fb, L, blk - 1024, t);   // H pass (F = d)
    } else {
        hd_ring<HW_, W_>(x, Md, thrs, fb, L, blk - 2048, t);   // D pass (F = h)
    }
}

// ---------------- 1x1x1 conv (64 -> 32); z2 = relu(max3(Mw,Mh,Md) - x) inline ----------------
__global__ __launch_bounds__(256, 4) void k_conv(const float* __restrict__ x,
                                                 const float* __restrict__ Mw, const float* __restrict__ Mh,
                                                 const float* __restrict__ Md,
                                                 const float* __restrict__ w, const float* __restrict__ bias,
                                                 float* __restrict__ y) {
    int t = threadIdx.x;
    int blk = blockIdx.x;                            // 0..2047
    int b = blk >> 10;
    int p0 = (blk & 1023) * 64;
    int og = __builtin_amdgcn_readfirstlane(t >> 6); // wave-uniform -> weights stay scalar
    int pl = t & 63;
    const float* xb = x + (size_t)b * CDHW_ + p0 + pl;
    size_t moff = ((size_t)b * 65536 + p0 + pl) * 32;
    const float4* mw = (const float4*)(Mw + moff);
    const float4* mh = (const float4*)(Mh + moff);
    const float4* md = (const float4*)(Md + moff);
    const float* wo = w + og * 512;                  // SGPR base -> s_load weights
    const float* bo = bias + og * 8;
    float a[8], xv[32];
#pragma unroll
    for (int k = 0; k < 8; ++k) a[k] = bo[k];
#pragma unroll
    for (int c = 0; c < 32; c += 4) {                // x half (L1-reused across the 4 waves)
        xv[c+0] = xb[(size_t)(c+0) * DHW_];
        xv[c+1] = xb[(size_t)(c+1) * DHW_];
        xv[c+2] = xb[(size_t)(c+2) * DHW_];
        xv[c+3] = xb[(size_t)(c+3) * DHW_];
#pragma unroll
        for (int k = 0; k < 8; ++k) {
            a[k] = fmaf(wo[k*64 + c+0], xv[c+0], a[k]);
            a[k] = fmaf(wo[k*64 + c+1], xv[c+1], a[k]);
            a[k] = fmaf(wo[k*64 + c+2], xv[c+2], a[k]);
            a[k] = fmaf(wo[k*64 + c+3], xv[c+3], a[k]);
        }
    }
#pragma unroll
    for (int q = 0; q < 8; ++q) {                    // z2 half (3x contiguous 128B/point + max3)
        float4 vw = mw[q], vh = mh[q], vd = md[q];
        float z0 = fmaxf(fmaxf(fmaxf(vw.x, vh.x), vd.x) - xv[4*q+0], 0.f);
        float z1 = fmaxf(fmaxf(fmaxf(vw.y, vh.y), vd.y) - xv[4*q+1], 0.f);
        float z2 = fmaxf(fmaxf(fmaxf(vw.z, vh.z), vd.z) - xv[4*q+2], 0.f);
        float z3 = fmaxf(fmaxf(fmaxf(vw.w, vh.w), vd.w) - xv[4*q+3], 0.f);
#pragma unroll
        for (int k = 0; k < 8; ++k) {
            a[k] = fmaf(wo[k*64 + 32 + q*4 + 0], z0, a[k]);
            a[k] = fmaf(wo[k*64 + 32 + q*4 + 1], z1, a[k]);
            a[k] = fmaf(wo[k*64 + 32 + q*4 + 2], z2, a[k]);
            a[k] = fmaf(wo[k*64 + 32 + q*4 + 3], z3, a[k]);
        }
    }
    float* yb = y + (size_t)b * CDHW_ + p0 + pl;
#pragma unroll
    for (int k = 0; k < 8; ++k) yb[(size_t)(og * 8 + k) * DHW_] = a[k];
}

// ---------------- BN batch stats from y -> per-block partials ----------------
__global__ __launch_bounds__(256) void k_stats(const float* __restrict__ y, double2* __restrict__ spart) {
    int o = blockIdx.y, ch = blockIdx.x;
    float s = 0.f, q = 0.f;
#pragma unroll
    for (int b = 0; b < 2; ++b) {
        const float4* yp = (const float4*)(y + (size_t)b * CDHW_ + (size_t)o * DHW_ + ch * 4096);
#pragma unroll
        for (int i = 0; i < 4; ++i) {
            float4 v = yp[i * 256 + threadIdx.x];
            s += ((v.x + v.y) + (v.z + v.w));
            q += ((v.x*v.x + v.y*v.y) + (v.z*v.z + v.w*v.w));
        }
    }
    double sd = s, qd = q;
    for (int off = 32; off; off >>= 1) {
        sd += __shfl_down(sd, off, 64);
        qd += __shfl_down(qd, off, 64);
    }
    __shared__ double ls[4], lq[4];
    int wv = threadIdx.x >> 6;
    if ((threadIdx.x & 63) == 0) { ls[wv] = sd; lq[wv] = qd; }
    __syncthreads();
    if (threadIdx.x == 0) {
        double2 out;
        out.x = (ls[0] + ls[1]) + (ls[2] + ls[3]);
        out.y = (lq[0] + lq[1]) + (lq[2] + lq[3]);
        spart[o * 16 + ch] = out;
    }
}

// ---------------- BN normalize + exact GELU, in-place ----------------
__global__ __launch_bounds__(256) void k_out(float* __restrict__ y, const double2* __restrict__ spart,
                                             const float* __restrict__ gamma, const float* __restrict__ beta) {
    int idx = blockIdx.x * 256 + threadIdx.x;       // over 1,048,576 float4
    int o = (blockIdx.x >> 6) & 31;                  // wave-uniform channel
    double sm = 0.0, sq = 0.0;
#pragma unroll
    for (int ch = 0; ch < 16; ++ch) {
        double2 v = spart[o * 16 + ch];
        sm += v.x; sq += v.y;
    }
    double mu = sm / (double)BN_N_;
    double var = sq / (double)BN_N_ - mu * mu;
    float rstd = (float)(1.0 / sqrt(var + 1e-5));
    float mu_f = (float)mu;
    float g = gamma[o], be = beta[o];
    float4 v = ((const float4*)y)[idx];
    float* vv = (float*)&v;
#pragma unroll
    for (int j = 0; j < 4; ++j) {
        float t = (vv[j] - mu_f) * rstd * g + be;
        vv[j] = 0.5f * t * (1.f + erff(t * 0.70710678118654752f));
    }
    ((float4*)y)[idx] = v;
}

extern "C" void kernel_launch(void* const* d_in, const int* in_sizes, int n_in,
                              void* d_out, int out_size, void* d_ws, size_t ws_size,
                              hipStream_t stream) {
    const float* x     = (const float*)d_in[0];
    const float* w     = (const float*)d_in[1];
    const float* bias  = (const float*)d_in[2];
    const float* gamma = (const float*)d_in[3];
    const float* beta  = (const float*)d_in[4];
    float* out = (float*)d_out;
    float* Mw = (float*)d_ws;
    float* Mh = (float*)((char*)d_ws + MH_OFF);
    float* Md = (float*)((char*)d_ws + MD_OFF);
    double2* npart = (double2*)((char*)d_ws + RED_OFF + 256);
    double2* spart = (double2*)((char*)d_ws + RED_OFF + 256 + 16384);

    k_norm  <<<1024, 256, 0, stream>>>(x, npart);
    k_passes<<<3072, 256, 0, stream>>>(x, npart, Mw, Mh, Md);
    k_conv  <<<2048, 256, 0, stream>>>(x, Mw, Mh, Md, w, bias, out);
    k_stats <<<dim3(16, 32), 256, 0, stream>>>(out, spart);
    k_out   <<<4096, 256, 0, stream>>>(out, spart, gamma, beta);
}